// Round 8
// baseline (824.397 us; speedup 1.0000x reference)
//
#include <hip/hip_runtime.h>
#include <hip/hip_bf16.h>
#include <math.h>

#define V 65536
#define G 2048
#define NPG 32
#define DEG 4
#define NE (V*DEG)
#define H 200
#define NODE_IN 74
#define EDGE_IN 12
#define NL 5

#define KP 224      // GEMM K padded (7 x 32)
#define NP 208      // feature dim padded (13 x 16)
#define AGSC 101    // chunked agg row stride in u32 (96 data + 5 pad)
#define EK 32       // edge-mfma K
#define HS 200      // h_s row stride (floats)

typedef __attribute__((ext_vector_type(8))) short short8;
typedef __attribute__((ext_vector_type(4))) float floatx4;
typedef __attribute__((ext_vector_type(2))) float float2v;

__device__ __forceinline__ float sigmoidf_(float x) { return 1.f / (1.f + __expf(-x)); }

__device__ __forceinline__ unsigned f2bf_bits(float f) {
    unsigned u = __float_as_uint(f);
    return (u + 0x7fffu + ((u >> 16) & 1u)) >> 16;  // RNE
}
__device__ __forceinline__ float bf2f(unsigned bits) { return __uint_as_float(bits << 16); }
__device__ __forceinline__ unsigned lo_bits(float f, unsigned hb) {
    return f2bf_bits(f - bf2f(hb));
}

// ---------------- fused prep + node embed: one launch, disjoint block ranges ----------------
#define EFB (NE / 256)               // 1024 edge-plane blocks
#define SEG_W (NL * NP * KP)
#define SEG_EW NP
#define WBLOCKS ((SEG_W + SEG_EW + 255) / 256)
#define EMBB (V / 16)
__global__ __launch_bounds__(256) void k_prep_embed(const float* __restrict__ ef,
                                                    const float* __restrict__ gnnW,
                                                    const float* __restrict__ eW,
                                                    const float* __restrict__ eb,
                                                    const float* __restrict__ nf,
                                                    const float* __restrict__ nW,
                                                    const float* __restrict__ nb,
                                                    unsigned short* __restrict__ Aedge,
                                                    unsigned short* __restrict__ WtHi,
                                                    unsigned short* __restrict__ WtLo,
                                                    unsigned short* __restrict__ eWp,
                                                    float* __restrict__ h) {
    __shared__ float smem[256 * EDGE_IN];   // 12 KB; embed path reuses as fs[16][NODE_IN]
    const int tid = threadIdx.x, blk = blockIdx.x;

    if (blk >= EFB + WBLOCKS) {
        float (*fs)[NODE_IN] = (float (*)[NODE_IN])smem;
        const int base = (blk - EFB - WBLOCKS) * 16;
        for (int p = tid; p < 16 * NODE_IN; p += 256) {
            int n = p / NODE_IN, i = p - n * NODE_IN;
            fs[n][i] = nf[(base + n) * NODE_IN + i];
        }
        __syncthreads();
        const int j = tid;
        if (j < H) {
            float acc[16];
#pragma unroll
            for (int n = 0; n < 16; n++) acc[n] = 0.f;
            for (int i = 0; i < NODE_IN; i++) {
                float w = nW[i * H + j];
#pragma unroll
                for (int n = 0; n < 16; n++) acc[n] = fmaf(fs[n][i], w, acc[n]);
            }
            float bj = nb[j];
            for (int n = 0; n < 16; n++) h[(base + n) * H + j] = acc[n] + bj;
        }
        return;
    }

    if (blk < EFB) {
        float* efs = smem;
        const float4* gs = (const float4*)(ef + (size_t)blk * 256 * EDGE_IN);
        float4* ds = (float4*)efs;
        for (int p = tid; p < 256 * EDGE_IN / 4; p += 256) ds[p] = gs[p];
        __syncthreads();
        unsigned hb[EDGE_IN], lb[EDGE_IN];
        for (int k = 0; k < EDGE_IN; k++) {
            float v = efs[tid * EDGE_IN + k];
            hb[k] = f2bf_bits(v);
            lb[k] = lo_bits(v, hb[k]);
        }
        unsigned w[16];
        for (int i = 0; i < 6; i++) w[i] = hb[2 * i] | (hb[2 * i + 1] << 16);
        for (int i = 0; i < 6; i++) w[6 + i] = lb[2 * i] | (lb[2 * i + 1] << 16);
        w[12] = 0x3F803F80u;
        w[13] = 0u; w[14] = 0u; w[15] = 0u;
        uint4* dst = (uint4*)(Aedge + ((size_t)blk * 256 + tid) * EK);
        dst[0] = make_uint4(w[0], w[1], w[2], w[3]);
        dst[1] = make_uint4(w[4], w[5], w[6], w[7]);
        dst[2] = make_uint4(w[8], w[9], w[10], w[11]);
        dst[3] = make_uint4(w[12], w[13], w[14], w[15]);
        return;
    }
    int idx = (blk - EFB) * 256 + tid;
    if (idx < SEG_W) {
        int l = idx / (NP * KP);
        int rem = idx - l * (NP * KP);
        int n = rem / KP;
        int k = rem - n * KP;
        float w = (n < H && k < H) ? gnnW[l * H * H + k * H + n] : 0.f;
        unsigned hb = f2bf_bits(w);
        WtHi[idx] = (unsigned short)hb;
        WtLo[idx] = (unsigned short)lo_bits(w, hb);
        return;
    }
    idx -= SEG_W;
    if (idx < SEG_EW) {
        int t = idx;
        unsigned short row[64];
        for (int i = 0; i < 64; i++) row[i] = 0;
        if (t < H) {
            for (int k = 0; k < EDGE_IN; k++) {
                float w = eW[k * H + t];
                unsigned hb = f2bf_bits(w);
                row[k] = (unsigned short)hb;
                row[12 + k] = (unsigned short)hb;
                row[32 + k] = (unsigned short)lo_bits(w, hb);
            }
            float e = eb[t];
            unsigned ebh = f2bf_bits(e);
            row[24] = (unsigned short)ebh;
            row[25] = (unsigned short)lo_bits(e, ebh);
        }
        for (int i = 0; i < 64; i++) eWp[t * 64 + i] = row[i];
    }
}

// ---------------- MEGA: 5 GNN layers + gf + attn(t=0) + hw1 epilogue ----------------
// R8: epilogue additionally computes hw1[v] = sum_j h[v][j]*lgW1[H+j] (the
// h-dependent part of the t=1 attention logit; lgW(t=1) is gf-independent),
// sharing the h_s reads with the attn0 z loop. Lets k_readout2 skip the z-pass
// h re-read entirely.
__global__ __launch_bounds__(256, 4) void k_mega(float* __restrict__ h,
                                                 const unsigned short* __restrict__ Aedge,
                                                 const unsigned short* __restrict__ eWp,
                                                 const int* __restrict__ src,
                                                 const unsigned short* __restrict__ WtHi,
                                                 const unsigned short* __restrict__ WtLo,
                                                 const float* __restrict__ gnn_b,
                                                 float* __restrict__ gf_out,
                                                 const float* __restrict__ lg_W,
                                                 const float* __restrict__ lg_b,
                                                 float* __restrict__ wh_out,
                                                 float* __restrict__ hw1_out) {
    __shared__ alignas(16) float h_s[NPG * HS];              // 25600 B
    __shared__ alignas(16) unsigned int aggc[NPG * AGSC];    // 12928 B
    __shared__ alignas(16) unsigned int zpad[8];
    __shared__ unsigned char src_s[NPG * DEG];
    const int g = blockIdx.x, tid = threadIdx.x;
    const int nbase = g * NPG, ebase = g * NPG * DEG;

    const int wave = tid >> 6, lane = tid & 63;
    const int l15 = lane & 15, quad = lane >> 4;
    const int ntcnt = (wave == 0) ? 4 : 3;

    const int mtA = wave * 2, mtB = mtA + 1;
    short8 afA, afB;
    {
        const unsigned short* abase = Aedge + (size_t)ebase * EK;
        afA = *(const short8*)&abase[(16 * mtA + l15) * EK + quad * 8];
        afB = *(const short8*)&abase[(16 * mtB + l15) * EK + quad * 8];
    }
    if (tid < NPG * DEG) src_s[tid] = (unsigned char)(src[ebase + tid] - nbase);
    if (tid < 8) zpad[tid] = 0u;
    {
        const float4* hsrc = (const float4*)(h + (size_t)nbase * H);
        float4* hdst = (float4*)h_s;
        for (int p = tid; p < NPG * H / 4; p += 256) hdst[p] = hsrc[p];
    }
    __syncthreads();

    const int nodeA = 4 * mtA + quad, nodeB = 4 * mtB + quad;
    int gsA[4], gsB[4];
#pragma unroll
    for (int e = 0; e < 4; e++) {
        gsA[e] = (int)src_s[nodeA * 4 + e] * HS;
        gsB[e] = (int)src_s[nodeB * 4 + e] * HS;
    }
    unsigned short* rowA = (unsigned short*)(aggc + nodeA * AGSC);
    unsigned short* rowB = (unsigned short*)(aggc + nodeB * AGSC);
    const float2v L2E2 = {1.4426950408889634f, 1.4426950408889634f};

    const int ntb0[3] = {0, 6, 10};
    const int ntb1[3] = {6, 10, 13};
    const int ksb0[3] = {0, 3, 5};
    const int ksb1[3] = {3, 5, 7};

    for (int l = 0; l < NL; l++) {
        floatx4 acc2[2][4];
#pragma unroll
        for (int mt = 0; mt < 2; mt++)
#pragma unroll
            for (int i = 0; i < 4; i++) acc2[mt][i] = (floatx4){0.f, 0.f, 0.f, 0.f};

        const unsigned short* WH = WtHi + (size_t)l * NP * KP;
        const unsigned short* WL = WtLo + (size_t)l * NP * KP;

        for (int ch = 0; ch < 3; ch++) {
            const int nt0 = ntb0[ch], nt1 = ntb1[ch];
            const int ks0 = ksb0[ch], ks1 = ksb1[ch];

            for (int nt = nt0; nt < nt1; nt++) {
                const int jj = nt * 16 + l15;
                const int jloc = jj - nt0 * 16;
                const int jc = jj < H ? jj : H - 1;
                const int colo = (jloc >> 3) * 16 + (jloc & 7);
                const bool val = (jj < H);
                short8 b1 = *(const short8*)&eWp[(size_t)jj * 64 + quad * 8];
                short8 b2 = *(const short8*)&eWp[(size_t)jj * 64 + 32 + quad * 8];

                auto unit = [&](short8 af, const int* gs, unsigned short* rowp) {
                    floatx4 z = (floatx4){0.f, 0.f, 0.f, 0.f};
                    z = __builtin_amdgcn_mfma_f32_16x16x32_bf16(af, b1, z, 0, 0, 0);
                    z = __builtin_amdgcn_mfma_f32_16x16x32_bf16(af, b2, z, 0, 0, 0);
                    floatx4 mh4;
#pragma unroll
                    for (int e = 0; e < 4; e++) mh4[e] = h_s[gs[e] + jc];
                    float2v mlo = __builtin_shufflevector(z, z, 0, 1) +
                                  __builtin_shufflevector(mh4, mh4, 0, 1);
                    float2v mhi = __builtin_shufflevector(z, z, 2, 3) +
                                  __builtin_shufflevector(mh4, mh4, 2, 3);
                    float mx = fmaxf(fmaxf(mlo[0], mlo[1]), fmaxf(mhi[0], mhi[1]));
                    float nm = -mx * 1.4426950408889634f;
                    float2v nm2 = {nm, nm};
                    float2v dlo = mlo * L2E2 + nm2;
                    float2v dhi = mhi * L2E2 + nm2;
                    floatx4 ev;
                    ev[0] = __builtin_amdgcn_exp2f(dlo[0]);
                    ev[1] = __builtin_amdgcn_exp2f(dlo[1]);
                    ev[2] = __builtin_amdgcn_exp2f(dhi[0]);
                    ev[3] = __builtin_amdgcn_exp2f(dhi[1]);
                    float2v elo = __builtin_shufflevector(ev, ev, 0, 1);
                    float2v ehi = __builtin_shufflevector(ev, ev, 2, 3);
                    float2v dsum = elo + ehi;
                    float2v nsum = mlo * elo + mhi * ehi;
                    float den = dsum[0] + dsum[1];
                    float num = nsum[0] + nsum[1];
                    float a = __fdividef(num, den);
                    if (!val) a = 0.f;
                    __bf16 bh = (__bf16)a;
                    float r = a - (float)bh;
                    __bf16 bl = (__bf16)r;
                    rowp[colo] = __builtin_bit_cast(unsigned short, bh);
                    rowp[colo + 8] = __builtin_bit_cast(unsigned short, bl);
                };
                unit(afA, gsA, rowA);
                unit(afB, gsB, rowB);
            }
            __syncthreads();

            for (int ks = ks0; ks < ks1; ks++) {
                const int c = 4 * ks + quad;
                const int cl = c - 4 * ks0;
                short8 ah[2], al[2];
#pragma unroll
                for (int mt = 0; mt < 2; mt++) {
                    const unsigned int* ap = (c < 26) ? &aggc[(16 * mt + l15) * AGSC + cl * 8]
                                                      : (const unsigned int*)zpad;
                    ah[mt] = *(const short8*)ap;
                    al[mt] = *(const short8*)(ap + 4);
                }
#pragma unroll 4
                for (int i = 0; i < ntcnt; i++) {
                    int nt = wave + 4 * i;
                    size_t boff = (size_t)(16 * nt + l15) * KP + ks * 32 + quad * 8;
                    short8 vbh = *(const short8*)&WH[boff];
                    short8 vbl = *(const short8*)&WL[boff];
#pragma unroll
                    for (int mt = 0; mt < 2; mt++) {
                        acc2[mt][i] = __builtin_amdgcn_mfma_f32_16x16x32_bf16(ah[mt], vbh, acc2[mt][i], 0, 0, 0);
                        acc2[mt][i] = __builtin_amdgcn_mfma_f32_16x16x32_bf16(al[mt], vbh, acc2[mt][i], 0, 0, 0);
                        acc2[mt][i] = __builtin_amdgcn_mfma_f32_16x16x32_bf16(ah[mt], vbl, acc2[mt][i], 0, 0, 0);
                    }
                }
            }

            if (ch == 2) {
                for (int i = 0; i < ntcnt; i++) {
                    int nt = wave + 4 * i, jj = nt * 16 + l15;
                    if (jj < H) {
                        float bj = gnn_b[l * H + jj];
#pragma unroll
                        for (int mt = 0; mt < 2; mt++) {
#pragma unroll
                            for (int r = 0; r < 4; r++) {
                                float v = acc2[mt][i][r] + bj;
                                v = v > 0.f ? v : 0.f;
                                h_s[(16 * mt + quad * 4 + r) * HS + jj] += v;
                            }
                        }
                    }
                }
            }
            __syncthreads();
        }
    }

    // ---- epilogue: h out, gf, attn(t=0), hw1 from LDS ----
    {
        float4* dst = (float4*)(h + (size_t)nbase * H);
        const float4* srcp = (const float4*)h_s;
        for (int p = tid; p < NPG * H / 4; p += 256) dst[p] = srcp[p];
    }
    const float* lgW0 = lg_W;
    const float* lgW1 = lg_W + 2 * H;
    float* gf_s = (float*)aggc;        // aggc dead now
    float* z_s = gf_s + 224;
    float* a_s = gf_s + 256;
    float* den_p = gf_s + 288;
    if (tid < H) {
        float s = 0.f;
        for (int n = 0; n < NPG; n++) s += h_s[n * HS + tid];
        gf_out[g * H + tid] = s;
        gf_s[tid] = s;
    }
    __syncthreads();
    {
        const int n = tid >> 3, l8 = tid & 7;
        float p = 0.f, p1 = 0.f;
        for (int jj = l8; jj < H; jj += 8) {
            float hv = h_s[n * HS + jj];
            p = fmaf(hv, lgW0[H + jj], p);
            p = fmaf(fmaxf(gf_s[jj], 0.f), lgW0[jj], p);
            p1 = fmaf(hv, lgW1[H + jj], p1);
        }
        p += __shfl_xor(p, 1);
        p += __shfl_xor(p, 2);
        p += __shfl_xor(p, 4);
        p1 += __shfl_xor(p1, 1);
        p1 += __shfl_xor(p1, 2);
        p1 += __shfl_xor(p1, 4);
        if (l8 == 0) {
            float z = p + lg_b[0];
            z_s[n] = z > 0.f ? z : 0.01f * z;
            hw1_out[nbase + n] = p1;
        }
    }
    __syncthreads();
    if (tid < 64) {
        float z = (lane < NPG) ? z_s[lane] : -1e30f;
        float m = z;
        m = fmaxf(m, __shfl_xor(m, 1));
        m = fmaxf(m, __shfl_xor(m, 2));
        m = fmaxf(m, __shfl_xor(m, 4));
        m = fmaxf(m, __shfl_xor(m, 8));
        m = fmaxf(m, __shfl_xor(m, 16));
        float e = (lane < NPG) ? __expf(z - m) : 0.f;
        float d = e;
        d += __shfl_xor(d, 1);
        d += __shfl_xor(d, 2);
        d += __shfl_xor(d, 4);
        d += __shfl_xor(d, 8);
        d += __shfl_xor(d, 16);
        if (lane < NPG) a_s[lane] = e;
        if (lane == 0) den_p[0] = d;
    }
    __syncthreads();
    if (tid < H) {
        float s = 0.f;
        for (int n = 0; n < NPG; n++) s = fmaf(a_s[n], h_s[n * HS + tid], s);
        wh_out[g * H + tid] = s / den_p[0];
    }
}

// ---------------- fused readout tail: pg(t=0) + attn(t=1) + pg(t=1) ----------------
// 8 graphs/block, 512 threads, 256 blocks. attn1 z uses precomputed hw1 (no h
// read); only the wh pass streams h (52MB, coalesced, once). softmax weights
// broadcast via shfl (no LDS RAW). pg math verbatim from proven k_projgru.
// LDS ~62.4KB -> 2 blocks/CU.
#define RGPB 8
#define RGP 9
__global__ __launch_bounds__(512) void k_readout2(const float* __restrict__ wh0,
                                                  const float* __restrict__ gf0,
                                                  const float* __restrict__ h,
                                                  const float* __restrict__ hw1,
                                                  const float* __restrict__ lg_W,
                                                  const float* __restrict__ lg_b,
                                                  const float* __restrict__ pr_W,
                                                  const float* __restrict__ pr_b,
                                                  const float* __restrict__ W_ih,
                                                  const float* __restrict__ W_hh,
                                                  const float* __restrict__ b_ih,
                                                  const float* __restrict__ b_hh,
                                                  float* __restrict__ out) {
    __shared__ float wh_s[RGPB][H];
    __shared__ float gfs[RGPB][H];
    __shared__ float ctx_s[RGPB][H];
    __shared__ float gi_s[3 * H][RGP];
    __shared__ float gh_s[3 * H][RGP];
    const int gbase = blockIdx.x * RGPB, tid = threadIdx.x;
    const int wq = tid >> 6, lane = tid & 63;

    for (int p = tid; p < RGPB * H; p += 512) {
        wh_s[0][p] = wh0[(size_t)gbase * H + p];
        gfs[0][p] = gf0[(size_t)gbase * H + p];
    }
    __syncthreads();

    for (int t = 0; t < 2; t++) {
        const float* prW = pr_W + (size_t)t * H * H;
        const float* prb = pr_b + (size_t)t * H;
        const float* Wih = W_ih + (size_t)t * 3 * H * H;
        const float* Whh = W_hh + (size_t)t * 3 * H * H;
        const float* bih = b_ih + (size_t)t * 3 * H;
        const float* bhh = b_hh + (size_t)t * 3 * H;

        if (t == 1) {
            // ---- attn(t=1): z from hw1 + relu(gf1)-term; wh streams h once ----
            const float* lgW1 = lg_W + 2 * H;
            const int g = gbase + wq;
            float sacc = 0.f;
            for (int j = lane; j < H; j += 64)
                sacc = fmaf(fmaxf(gfs[wq][j], 0.f), lgW1[j], sacc);
            sacc += __shfl_xor(sacc, 1);
            sacc += __shfl_xor(sacc, 2);
            sacc += __shfl_xor(sacc, 4);
            sacc += __shfl_xor(sacc, 8);
            sacc += __shfl_xor(sacc, 16);
            sacc += __shfl_xor(sacc, 32);
            float z = -1e30f;
            if (lane < NPG) {
                z = hw1[(size_t)g * NPG + lane] + sacc + lg_b[1];
                z = z > 0.f ? z : 0.01f * z;
            }
            float m = z;
            m = fmaxf(m, __shfl_xor(m, 1));
            m = fmaxf(m, __shfl_xor(m, 2));
            m = fmaxf(m, __shfl_xor(m, 4));
            m = fmaxf(m, __shfl_xor(m, 8));
            m = fmaxf(m, __shfl_xor(m, 16));
            float e = (lane < NPG) ? __expf(z - m) : 0.f;
            float d = e;
            d += __shfl_xor(d, 1);
            d += __shfl_xor(d, 2);
            d += __shfl_xor(d, 4);
            d += __shfl_xor(d, 8);
            d += __shfl_xor(d, 16);
            float den = __shfl(d, 0);
            float w0 = 0.f, w1 = 0.f, w2 = 0.f, w3 = 0.f;
            const float* hg = h + (size_t)g * NPG * H;
            for (int n = 0; n < NPG; n++) {
                float a = __shfl(e, n);
                const float* hr = hg + n * H;
                w0 = fmaf(a, hr[lane], w0);
                w1 = fmaf(a, hr[lane + 64], w1);
                w2 = fmaf(a, hr[lane + 128], w2);
                if (lane < 8) w3 = fmaf(a, hr[lane + 192], w3);
            }
            wh_s[wq][lane] = w0 / den;
            wh_s[wq][lane + 64] = w1 / den;
            wh_s[wq][lane + 128] = w2 / den;
            if (lane < 8) wh_s[wq][lane + 192] = w3 / den;
            __syncthreads();
        }

        // ---- proj: ctx = elu(wh @ prW + prb) ----
        {
            const int j = tid;
            if (j < H) {
                float acc[RGPB];
#pragma unroll
                for (int q = 0; q < RGPB; q++) acc[q] = 0.f;
                for (int i = 0; i < H; i++) {
                    float w = prW[i * H + j];
#pragma unroll
                    for (int q = 0; q < RGPB; q++) acc[q] = fmaf(wh_s[q][i], w, acc[q]);
                }
                float bj = prb[j];
                for (int q = 0; q < RGPB; q++) {
                    float s = acc[q] + bj;
                    ctx_s[q][j] = s > 0.f ? s : __expf(s) - 1.f;
                }
            }
        }
        __syncthreads();

        // ---- gru gates ----
        for (int k = tid; k < 3 * H; k += 512) {
            float ai[RGPB], ah[RGPB];
            float bi = bih[k], bh = bhh[k];
#pragma unroll
            for (int q = 0; q < RGPB; q++) { ai[q] = bi; ah[q] = bh; }
            const float4* wi4 = (const float4*)(Wih + (size_t)k * H);
            const float4* wh4 = (const float4*)(Whh + (size_t)k * H);
            for (int j4 = 0; j4 < H / 4; j4++) {
                float4 wi = wi4[j4];
                float4 wg = wh4[j4];
                int jj = j4 * 4;
#pragma unroll
                for (int q = 0; q < RGPB; q++) {
                    ai[q] = fmaf(ctx_s[q][jj + 0], wi.x, ai[q]);
                    ai[q] = fmaf(ctx_s[q][jj + 1], wi.y, ai[q]);
                    ai[q] = fmaf(ctx_s[q][jj + 2], wi.z, ai[q]);
                    ai[q] = fmaf(ctx_s[q][jj + 3], wi.w, ai[q]);
                    ah[q] = fmaf(gfs[q][jj + 0], wg.x, ah[q]);
                    ah[q] = fmaf(gfs[q][jj + 1], wg.y, ah[q]);
                    ah[q] = fmaf(gfs[q][jj + 2], wg.z, ah[q]);
                    ah[q] = fmaf(gfs[q][jj + 3], wg.w, ah[q]);
                }
            }
#pragma unroll
            for (int q = 0; q < RGPB; q++) { gi_s[k][q] = ai[q]; gh_s[k][q] = ah[q]; }
        }
        __syncthreads();

        // ---- gru update ----
        for (int p = tid; p < RGPB * H; p += 512) {
            int q = p / H, jj = p - q * H;
            float r = sigmoidf_(gi_s[jj][q] + gh_s[jj][q]);
            float u = sigmoidf_(gi_s[H + jj][q] + gh_s[H + jj][q]);
            float nn = tanhf(gi_s[2 * H + jj][q] + r * gh_s[2 * H + jj][q]);
            float res = (1.f - u) * nn + u * gfs[q][jj];
            if (t == 0) gfs[q][jj] = res;
            else out[(size_t)(gbase + q) * H + jj] = res;
        }
        __syncthreads();
    }
}

extern "C" void kernel_launch(void* const* d_in, const int* in_sizes, int n_in,
                              void* d_out, int out_size, void* d_ws, size_t ws_size,
                              hipStream_t stream) {
    const float* node_feat = (const float*)d_in[0];
    const float* edge_feat = (const float*)d_in[1];
    const int* src = (const int*)d_in[2];
    const float* node_W = (const float*)d_in[5];
    const float* node_b = (const float*)d_in[6];
    const float* edge_W = (const float*)d_in[7];
    const float* edge_b = (const float*)d_in[8];
    const float* gnn_W = (const float*)d_in[9];
    const float* gnn_b = (const float*)d_in[10];
    const float* lg_W = (const float*)d_in[11];
    const float* lg_b = (const float*)d_in[12];
    const float* pr_W = (const float*)d_in[13];
    const float* pr_b = (const float*)d_in[14];
    const float* W_ih = (const float*)d_in[15];
    const float* W_hh = (const float*)d_in[16];
    const float* b_ih = (const float*)d_in[17];
    const float* b_hh = (const float*)d_in[18];
    float* out = (float*)d_out;

    char* ws = (char*)d_ws;
    size_t off = 0;
    auto alloc = [&](size_t bytes) { void* p = ws + off; off += (bytes + 4095) & ~(size_t)4095; return p; };
    float* h = (float*)alloc((size_t)V * H * 4);
    unsigned short* Aedge = (unsigned short*)alloc((size_t)NE * EK * 2);
    unsigned short* WtHi = (unsigned short*)alloc((size_t)NL * NP * KP * 2);
    unsigned short* WtLo = (unsigned short*)alloc((size_t)NL * NP * KP * 2);
    unsigned short* eWp = (unsigned short*)alloc((size_t)NP * 64 * 2);
    float* gf_ws = (float*)alloc((size_t)G * H * 4);
    float* wh_ws = (float*)alloc((size_t)G * H * 4);
    float* hw1_ws = (float*)alloc((size_t)V * 4);

    k_prep_embed<<<EFB + WBLOCKS + EMBB, 256, 0, stream>>>(
        edge_feat, gnn_W, edge_W, edge_b, node_feat, node_W, node_b,
        Aedge, WtHi, WtLo, eWp, h);

    k_mega<<<G, 256, 0, stream>>>(h, Aedge, eWp, src, WtHi, WtLo, gnn_b, gf_ws,
                                  lg_W, lg_b, wh_ws, hw1_ws);

    k_readout2<<<G / RGPB, 512, 0, stream>>>(wh_ws, gf_ws, h, hw1_ws,
                                             lg_W, lg_b, pr_W, pr_b,
                                             W_ih, W_hh, b_ih, b_hh, out);
}

// Round 10
// 579.070 us; speedup vs baseline: 1.4237x; 1.4237x over previous
//
#include <hip/hip_runtime.h>
#include <hip/hip_bf16.h>
#include <math.h>

#define V 65536
#define G 2048
#define NPG 32
#define DEG 4
#define NE (V*DEG)
#define H 200
#define NODE_IN 74
#define EDGE_IN 12
#define NL 5

#define KP 224      // GEMM K padded (7 x 32)
#define NP 208      // feature dim padded (13 x 16)
#define AGSC 101    // chunked agg row stride in u32 (96 data + 5 pad)
#define EK 32       // edge-mfma K
#define HS 200      // h_s row stride (floats)

typedef __attribute__((ext_vector_type(8))) short short8;
typedef __attribute__((ext_vector_type(4))) float floatx4;
typedef __attribute__((ext_vector_type(2))) float float2v;

__device__ __forceinline__ float sigmoidf_(float x) { return 1.f / (1.f + __expf(-x)); }

__device__ __forceinline__ unsigned f2bf_bits(float f) {
    unsigned u = __float_as_uint(f);
    return (u + 0x7fffu + ((u >> 16) & 1u)) >> 16;  // RNE
}
__device__ __forceinline__ float bf2f(unsigned bits) { return __uint_as_float(bits << 16); }
__device__ __forceinline__ unsigned lo_bits(float f, unsigned hb) {
    return f2bf_bits(f - bf2f(hb));
}

// ---------------- fused prep + node embed (R7 version, no transpose) ----------------
#define EFB (NE / 256)               // 1024 edge-plane blocks
#define SEG_W (NL * NP * KP)
#define SEG_EW NP
#define WBLOCKS ((SEG_W + SEG_EW + 255) / 256)
#define EMBB (V / 16)
__global__ __launch_bounds__(256) void k_prep_embed(const float* __restrict__ ef,
                                                    const float* __restrict__ gnnW,
                                                    const float* __restrict__ eW,
                                                    const float* __restrict__ eb,
                                                    const float* __restrict__ nf,
                                                    const float* __restrict__ nW,
                                                    const float* __restrict__ nb,
                                                    unsigned short* __restrict__ Aedge,
                                                    unsigned short* __restrict__ WtHi,
                                                    unsigned short* __restrict__ WtLo,
                                                    unsigned short* __restrict__ eWp,
                                                    float* __restrict__ h) {
    __shared__ float smem[256 * EDGE_IN];   // 12 KB; embed path reuses as fs[16][NODE_IN]
    const int tid = threadIdx.x, blk = blockIdx.x;

    if (blk >= EFB + WBLOCKS) {
        // ---- node embedding (fp32) ----
        float (*fs)[NODE_IN] = (float (*)[NODE_IN])smem;
        const int base = (blk - EFB - WBLOCKS) * 16;
        for (int p = tid; p < 16 * NODE_IN; p += 256) {
            int n = p / NODE_IN, i = p - n * NODE_IN;
            fs[n][i] = nf[(base + n) * NODE_IN + i];
        }
        __syncthreads();
        const int j = tid;
        if (j < H) {
            float acc[16];
#pragma unroll
            for (int n = 0; n < 16; n++) acc[n] = 0.f;
            for (int i = 0; i < NODE_IN; i++) {
                float w = nW[i * H + j];
#pragma unroll
                for (int n = 0; n < 16; n++) acc[n] = fmaf(fs[n][i], w, acc[n]);
            }
            float bj = nb[j];
            for (int n = 0; n < 16; n++) h[(base + n) * H + j] = acc[n] + bj;
        }
        return;
    }

    if (blk < EFB) {
        float* efs = smem;
        const float4* gs = (const float4*)(ef + (size_t)blk * 256 * EDGE_IN);
        float4* ds = (float4*)efs;
        for (int p = tid; p < 256 * EDGE_IN / 4; p += 256) ds[p] = gs[p];
        __syncthreads();
        unsigned hb[EDGE_IN], lb[EDGE_IN];
        for (int k = 0; k < EDGE_IN; k++) {
            float v = efs[tid * EDGE_IN + k];
            hb[k] = f2bf_bits(v);
            lb[k] = lo_bits(v, hb[k]);
        }
        unsigned w[16];
        for (int i = 0; i < 6; i++) w[i] = hb[2 * i] | (hb[2 * i + 1] << 16);
        for (int i = 0; i < 6; i++) w[6 + i] = lb[2 * i] | (lb[2 * i + 1] << 16);
        w[12] = 0x3F803F80u;
        w[13] = 0u; w[14] = 0u; w[15] = 0u;
        uint4* dst = (uint4*)(Aedge + ((size_t)blk * 256 + tid) * EK);
        dst[0] = make_uint4(w[0], w[1], w[2], w[3]);
        dst[1] = make_uint4(w[4], w[5], w[6], w[7]);
        dst[2] = make_uint4(w[8], w[9], w[10], w[11]);
        dst[3] = make_uint4(w[12], w[13], w[14], w[15]);
        return;
    }
    int idx = (blk - EFB) * 256 + tid;
    if (idx < SEG_W) {
        int l = idx / (NP * KP);
        int rem = idx - l * (NP * KP);
        int n = rem / KP;
        int k = rem - n * KP;
        float w = (n < H && k < H) ? gnnW[l * H * H + k * H + n] : 0.f;
        unsigned hb = f2bf_bits(w);
        WtHi[idx] = (unsigned short)hb;
        WtLo[idx] = (unsigned short)lo_bits(w, hb);
        return;
    }
    idx -= SEG_W;
    if (idx < SEG_EW) {
        int t = idx;
        unsigned short row[64];
        for (int i = 0; i < 64; i++) row[i] = 0;
        if (t < H) {
            for (int k = 0; k < EDGE_IN; k++) {
                float w = eW[k * H + t];
                unsigned hb = f2bf_bits(w);
                row[k] = (unsigned short)hb;
                row[12 + k] = (unsigned short)hb;
                row[32 + k] = (unsigned short)lo_bits(w, hb);
            }
            float e = eb[t];
            unsigned ebh = f2bf_bits(e);
            row[24] = (unsigned short)ebh;
            row[25] = (unsigned short)lo_bits(e, ebh);
        }
        for (int i = 0; i < 64; i++) eWp[t * 64 + i] = row[i];
    }
}

// ---------------- MEGA: 5 GNN layers + gf + attn(t=0) epilogue (unchanged) ----------------
__global__ __launch_bounds__(256, 4) void k_mega(float* __restrict__ h,
                                                 const unsigned short* __restrict__ Aedge,
                                                 const unsigned short* __restrict__ eWp,
                                                 const int* __restrict__ src,
                                                 const unsigned short* __restrict__ WtHi,
                                                 const unsigned short* __restrict__ WtLo,
                                                 const float* __restrict__ gnn_b,
                                                 float* __restrict__ gf_out,
                                                 const float* __restrict__ lgW,
                                                 const float* __restrict__ lgb,
                                                 float* __restrict__ wh_out) {
    __shared__ alignas(16) float h_s[NPG * HS];              // 25600 B
    __shared__ alignas(16) unsigned int aggc[NPG * AGSC];    // 12928 B
    __shared__ alignas(16) unsigned int zpad[8];
    __shared__ unsigned char src_s[NPG * DEG];
    const int g = blockIdx.x, tid = threadIdx.x;
    const int nbase = g * NPG, ebase = g * NPG * DEG;

    const int wave = tid >> 6, lane = tid & 63;
    const int l15 = lane & 15, quad = lane >> 4;
    const int ntcnt = (wave == 0) ? 4 : 3;

    const int mtA = wave * 2, mtB = mtA + 1;
    short8 afA, afB;
    {
        const unsigned short* abase = Aedge + (size_t)ebase * EK;
        afA = *(const short8*)&abase[(16 * mtA + l15) * EK + quad * 8];
        afB = *(const short8*)&abase[(16 * mtB + l15) * EK + quad * 8];
    }
    if (tid < NPG * DEG) src_s[tid] = (unsigned char)(src[ebase + tid] - nbase);
    if (tid < 8) zpad[tid] = 0u;
    {
        const float4* hsrc = (const float4*)(h + (size_t)nbase * H);
        float4* hdst = (float4*)h_s;
        for (int p = tid; p < NPG * H / 4; p += 256) hdst[p] = hsrc[p];
    }
    __syncthreads();

    const int nodeA = 4 * mtA + quad, nodeB = 4 * mtB + quad;
    int gsA[4], gsB[4];
#pragma unroll
    for (int e = 0; e < 4; e++) {
        gsA[e] = (int)src_s[nodeA * 4 + e] * HS;
        gsB[e] = (int)src_s[nodeB * 4 + e] * HS;
    }
    unsigned short* rowA = (unsigned short*)(aggc + nodeA * AGSC);
    unsigned short* rowB = (unsigned short*)(aggc + nodeB * AGSC);
    const float2v L2E2 = {1.4426950408889634f, 1.4426950408889634f};

    const int ntb0[3] = {0, 6, 10};
    const int ntb1[3] = {6, 10, 13};
    const int ksb0[3] = {0, 3, 5};
    const int ksb1[3] = {3, 5, 7};

    for (int l = 0; l < NL; l++) {
        floatx4 acc2[2][4];
#pragma unroll
        for (int mt = 0; mt < 2; mt++)
#pragma unroll
            for (int i = 0; i < 4; i++) acc2[mt][i] = (floatx4){0.f, 0.f, 0.f, 0.f};

        const unsigned short* WH = WtHi + (size_t)l * NP * KP;
        const unsigned short* WL = WtLo + (size_t)l * NP * KP;

        for (int ch = 0; ch < 3; ch++) {
            const int nt0 = ntb0[ch], nt1 = ntb1[ch];
            const int ks0 = ksb0[ch], ks1 = ksb1[ch];

            for (int nt = nt0; nt < nt1; nt++) {
                const int jj = nt * 16 + l15;
                const int jloc = jj - nt0 * 16;
                const int jc = jj < H ? jj : H - 1;
                const int colo = (jloc >> 3) * 16 + (jloc & 7);
                const bool val = (jj < H);
                short8 b1 = *(const short8*)&eWp[(size_t)jj * 64 + quad * 8];
                short8 b2 = *(const short8*)&eWp[(size_t)jj * 64 + 32 + quad * 8];

                auto unit = [&](short8 af, const int* gs, unsigned short* rowp) {
                    floatx4 z = (floatx4){0.f, 0.f, 0.f, 0.f};
                    z = __builtin_amdgcn_mfma_f32_16x16x32_bf16(af, b1, z, 0, 0, 0);
                    z = __builtin_amdgcn_mfma_f32_16x16x32_bf16(af, b2, z, 0, 0, 0);
                    floatx4 mh4;
#pragma unroll
                    for (int e = 0; e < 4; e++) mh4[e] = h_s[gs[e] + jc];
                    float2v mlo = __builtin_shufflevector(z, z, 0, 1) +
                                  __builtin_shufflevector(mh4, mh4, 0, 1);
                    float2v mhi = __builtin_shufflevector(z, z, 2, 3) +
                                  __builtin_shufflevector(mh4, mh4, 2, 3);
                    float mx = fmaxf(fmaxf(mlo[0], mlo[1]), fmaxf(mhi[0], mhi[1]));
                    float nm = -mx * 1.4426950408889634f;
                    float2v nm2 = {nm, nm};
                    float2v dlo = mlo * L2E2 + nm2;
                    float2v dhi = mhi * L2E2 + nm2;
                    floatx4 ev;
                    ev[0] = __builtin_amdgcn_exp2f(dlo[0]);
                    ev[1] = __builtin_amdgcn_exp2f(dlo[1]);
                    ev[2] = __builtin_amdgcn_exp2f(dhi[0]);
                    ev[3] = __builtin_amdgcn_exp2f(dhi[1]);
                    float2v elo = __builtin_shufflevector(ev, ev, 0, 1);
                    float2v ehi = __builtin_shufflevector(ev, ev, 2, 3);
                    float2v dsum = elo + ehi;
                    float2v nsum = mlo * elo + mhi * ehi;
                    float den = dsum[0] + dsum[1];
                    float num = nsum[0] + nsum[1];
                    float a = __fdividef(num, den);
                    if (!val) a = 0.f;
                    __bf16 bh = (__bf16)a;
                    float r = a - (float)bh;
                    __bf16 bl = (__bf16)r;
                    rowp[colo] = __builtin_bit_cast(unsigned short, bh);
                    rowp[colo + 8] = __builtin_bit_cast(unsigned short, bl);
                };
                unit(afA, gsA, rowA);
                unit(afB, gsB, rowB);
            }
            __syncthreads();

            for (int ks = ks0; ks < ks1; ks++) {
                const int c = 4 * ks + quad;
                const int cl = c - 4 * ks0;
                short8 ah[2], al[2];
#pragma unroll
                for (int mt = 0; mt < 2; mt++) {
                    const unsigned int* ap = (c < 26) ? &aggc[(16 * mt + l15) * AGSC + cl * 8]
                                                      : (const unsigned int*)zpad;
                    ah[mt] = *(const short8*)ap;
                    al[mt] = *(const short8*)(ap + 4);
                }
#pragma unroll 4
                for (int i = 0; i < ntcnt; i++) {
                    int nt = wave + 4 * i;
                    size_t boff = (size_t)(16 * nt + l15) * KP + ks * 32 + quad * 8;
                    short8 vbh = *(const short8*)&WH[boff];
                    short8 vbl = *(const short8*)&WL[boff];
#pragma unroll
                    for (int mt = 0; mt < 2; mt++) {
                        acc2[mt][i] = __builtin_amdgcn_mfma_f32_16x16x32_bf16(ah[mt], vbh, acc2[mt][i], 0, 0, 0);
                        acc2[mt][i] = __builtin_amdgcn_mfma_f32_16x16x32_bf16(al[mt], vbh, acc2[mt][i], 0, 0, 0);
                        acc2[mt][i] = __builtin_amdgcn_mfma_f32_16x16x32_bf16(ah[mt], vbl, acc2[mt][i], 0, 0, 0);
                    }
                }
            }

            if (ch == 2) {
                for (int i = 0; i < ntcnt; i++) {
                    int nt = wave + 4 * i, jj = nt * 16 + l15;
                    if (jj < H) {
                        float bj = gnn_b[l * H + jj];
#pragma unroll
                        for (int mt = 0; mt < 2; mt++) {
#pragma unroll
                            for (int r = 0; r < 4; r++) {
                                float v = acc2[mt][i][r] + bj;
                                v = v > 0.f ? v : 0.f;
                                h_s[(16 * mt + quad * 4 + r) * HS + jj] += v;
                            }
                        }
                    }
                }
            }
            __syncthreads();
        }
    }

    // ---- epilogue: h out, gf, attn(t=0) from LDS ----
    {
        float4* dst = (float4*)(h + (size_t)nbase * H);
        const float4* srcp = (const float4*)h_s;
        for (int p = tid; p < NPG * H / 4; p += 256) dst[p] = srcp[p];
    }
    float* gf_s = (float*)aggc;        // aggc dead now
    float* z_s = gf_s + 224;
    float* a_s = gf_s + 256;
    float* den_p = gf_s + 288;
    if (tid < H) {
        float s = 0.f;
        for (int n = 0; n < NPG; n++) s += h_s[n * HS + tid];
        gf_out[g * H + tid] = s;
        gf_s[tid] = s;
    }
    __syncthreads();
    {
        const int n = tid >> 3, l8 = tid & 7;
        float p = 0.f;
        for (int jj = l8; jj < H; jj += 8) {
            p = fmaf(h_s[n * HS + jj], lgW[H + jj], p);
            p = fmaf(fmaxf(gf_s[jj], 0.f), lgW[jj], p);
        }
        p += __shfl_xor(p, 1);
        p += __shfl_xor(p, 2);
        p += __shfl_xor(p, 4);
        if (l8 == 0) {
            float z = p + lgb[0];
            z_s[n] = z > 0.f ? z : 0.01f * z;
        }
    }
    __syncthreads();
    if (tid < 64) {
        float z = (lane < NPG) ? z_s[lane] : -1e30f;
        float m = z;
        m = fmaxf(m, __shfl_xor(m, 1));
        m = fmaxf(m, __shfl_xor(m, 2));
        m = fmaxf(m, __shfl_xor(m, 4));
        m = fmaxf(m, __shfl_xor(m, 8));
        m = fmaxf(m, __shfl_xor(m, 16));
        float e = (lane < NPG) ? __expf(z - m) : 0.f;
        float d = e;
        d += __shfl_xor(d, 1);
        d += __shfl_xor(d, 2);
        d += __shfl_xor(d, 4);
        d += __shfl_xor(d, 8);
        d += __shfl_xor(d, 16);
        if (lane < NPG) a_s[lane] = e;
        if (lane == 0) den_p[0] = d;
    }
    __syncthreads();
    if (tid < H) {
        float s = 0.f;
        for (int n = 0; n < NPG; n++) s = fmaf(a_s[n], h_s[n * HS + tid], s);
        wh_out[g * H + tid] = s / den_p[0];
    }
}

// ---------------- gate-weight transpose (runs AFTER k_mega; writes into dead Aedge) ----------------
// WgT[t][(j*600 + k)*2 + m] = Wm[t][k][j], m in {0=ih, 1=hh}. 1.92MB < Aedge's 16.8MB.
// Separate kernel (not fused into prep) so workspace footprint stays at the
// R7-proven 70.0 MiB — R9 grew it by 1.92MB and the post-timing check
// diverged with the signature of out-of-workspace corruption.
#define SEG_T (2 * 2 * 3 * H * H)    // 480000
#define TBLOCKS ((SEG_T + 255) / 256)
__global__ __launch_bounds__(256) void k_wgt(const float* __restrict__ W_ih,
                                             const float* __restrict__ W_hh,
                                             float* __restrict__ WgT) {
    int idx = blockIdx.x * 256 + threadIdx.x;
    if (idx < SEG_T) {
        int tt = idx / (2 * 3 * H * H);          // 240000 per t
        int r = idx - tt * (2 * 3 * H * H);
        int j = r / (6 * H);                     // 1200 per j
        int r2 = r - j * (6 * H);
        int k = r2 >> 1;
        int m = r2 & 1;
        const float* srcm = (m ? W_hh : W_ih) + (size_t)tt * 3 * H * H;
        WgT[idx] = srcm[k * H + j];              // writes coalesced
    }
}

// ---------------- readout attention (t=1 only, unchanged) ----------------
__global__ __launch_bounds__(256) void k_attn(const float* __restrict__ h,
                                              const float* __restrict__ gf,
                                              const float* __restrict__ lgW,
                                              const float* __restrict__ lgb,
                                              float* __restrict__ wh_out) {
    __shared__ float h_s[NPG][H];
    __shared__ float gf_s[H];
    __shared__ float z_s[NPG];
    __shared__ float a_s[NPG];
    __shared__ float den_s;
    const int g = blockIdx.x, tid = threadIdx.x;
    const int lane = tid & 63;

    for (int p = tid; p < NPG * H; p += 256) h_s[0][p] = h[g * NPG * H + p];
    if (tid < H) gf_s[tid] = gf[g * H + tid];
    __syncthreads();

    {
        const int n = tid >> 3, l = tid & 7;
        float p = 0.f;
        for (int jj = l; jj < H; jj += 8) {
            p = fmaf(h_s[n][jj], lgW[H + jj], p);
            p = fmaf(fmaxf(gf_s[jj], 0.f), lgW[jj], p);
        }
        p += __shfl_xor(p, 1);
        p += __shfl_xor(p, 2);
        p += __shfl_xor(p, 4);
        if (l == 0) {
            float z = p + lgb[0];
            z_s[n] = z > 0.f ? z : 0.01f * z;
        }
    }
    __syncthreads();

    if (tid < 64) {
        float z = (lane < NPG) ? z_s[lane] : -1e30f;
        float m = z;
        m = fmaxf(m, __shfl_xor(m, 1));
        m = fmaxf(m, __shfl_xor(m, 2));
        m = fmaxf(m, __shfl_xor(m, 4));
        m = fmaxf(m, __shfl_xor(m, 8));
        m = fmaxf(m, __shfl_xor(m, 16));
        float e = (lane < NPG) ? __expf(z - m) : 0.f;
        float d = e;
        d += __shfl_xor(d, 1);
        d += __shfl_xor(d, 2);
        d += __shfl_xor(d, 4);
        d += __shfl_xor(d, 8);
        d += __shfl_xor(d, 16);
        if (lane < NPG) a_s[lane] = e;
        if (lane == 0) den_s = d;
    }
    __syncthreads();

    if (tid < H) {
        float s = 0.f;
        for (int n = 0; n < NPG; n++) s = fmaf(a_s[n], h_s[n][tid], s);
        wh_out[g * H + tid] = s / den_s;
    }
}

// ---------------- proj+GRU (R9 version: coalesced transposed gate weights) ----------------
#define GPB 8
#define GP 9
__global__ __launch_bounds__(512) void k_projgru(const float* __restrict__ wh,
                                                 const float* __restrict__ gf,
                                                 const float* __restrict__ prW,
                                                 const float* __restrict__ prb,
                                                 const float* __restrict__ WgTt,
                                                 const float* __restrict__ bih,
                                                 const float* __restrict__ bhh,
                                                 float* __restrict__ gf_out) {
    __shared__ float wh_s[GPB][H];
    __shared__ float gfs[GPB][H];
    __shared__ float ctx_s[GPB][H];
    __shared__ float gi_s[3 * H][GP];
    __shared__ float gh_s[3 * H][GP];
    const int gbase = blockIdx.x * GPB, tid = threadIdx.x;

    for (int p = tid; p < GPB * H; p += 512) {
        wh_s[0][p] = wh[(size_t)gbase * H + p];
        gfs[0][p] = gf[(size_t)gbase * H + p];
    }
    __syncthreads();

    // ---- proj: ctx = elu(wh @ prW + prb); 100 threads x 2 outputs ----
    if (tid < 100) {
        const int j = tid;
        float a0[GPB], a1[GPB];
#pragma unroll
        for (int q = 0; q < GPB; q++) { a0[q] = 0.f; a1[q] = 0.f; }
        for (int c = 0; c < H / 4; c++) {
            const int i = c * 4;
            float wv[GPB][4];
#pragma unroll
            for (int q = 0; q < GPB; q++) {
                float4 t4 = *(const float4*)&wh_s[q][i];
                wv[q][0] = t4.x; wv[q][1] = t4.y; wv[q][2] = t4.z; wv[q][3] = t4.w;
            }
#pragma unroll
            for (int jj = 0; jj < 4; jj++) {
                float wA = prW[(i + jj) * H + j];
                float wB = prW[(i + jj) * H + j + 100];
#pragma unroll
                for (int q = 0; q < GPB; q++) {
                    a0[q] = fmaf(wv[q][jj], wA, a0[q]);
                    a1[q] = fmaf(wv[q][jj], wB, a1[q]);
                }
            }
        }
        float b0 = prb[j], b1 = prb[j + 100];
#pragma unroll
        for (int q = 0; q < GPB; q++) {
            float s0 = a0[q] + b0;
            float s1 = a1[q] + b1;
            ctx_s[q][j] = s0 > 0.f ? s0 : __expf(s0) - 1.f;
            ctx_s[q][j + 100] = s1 > 0.f ? s1 : __expf(s1) - 1.f;
        }
    }
    __syncthreads();

    // ---- gru gates: 300 threads x 2 rows, coalesced WgT float2 loads ----
    if (tid < 300) {
        const int k0 = tid, k1 = tid + 300;
        float ai0[GPB], ah0[GPB], ai1[GPB], ah1[GPB];
        float bi0 = bih[k0], bh0 = bhh[k0], bi1 = bih[k1], bh1 = bhh[k1];
#pragma unroll
        for (int q = 0; q < GPB; q++) { ai0[q] = bi0; ah0[q] = bh0; ai1[q] = bi1; ah1[q] = bh1; }
        for (int c = 0; c < H / 4; c++) {
            const int j = c * 4;
            float cx[GPB][4], gg[GPB][4];
#pragma unroll
            for (int q = 0; q < GPB; q++) {
                float4 t4 = *(const float4*)&ctx_s[q][j];
                cx[q][0] = t4.x; cx[q][1] = t4.y; cx[q][2] = t4.z; cx[q][3] = t4.w;
                float4 g4 = *(const float4*)&gfs[q][j];
                gg[q][0] = g4.x; gg[q][1] = g4.y; gg[q][2] = g4.z; gg[q][3] = g4.w;
            }
#pragma unroll
            for (int jj = 0; jj < 4; jj++) {
                float2 wa = *(const float2*)&WgTt[((size_t)(j + jj) * 600 + k0) * 2];
                float2 wb = *(const float2*)&WgTt[((size_t)(j + jj) * 600 + k1) * 2];
#pragma unroll
                for (int q = 0; q < GPB; q++) {
                    ai0[q] = fmaf(cx[q][jj], wa.x, ai0[q]);
                    ah0[q] = fmaf(gg[q][jj], wa.y, ah0[q]);
                    ai1[q] = fmaf(cx[q][jj], wb.x, ai1[q]);
                    ah1[q] = fmaf(gg[q][jj], wb.y, ah1[q]);
                }
            }
        }
#pragma unroll
        for (int q = 0; q < GPB; q++) {
            gi_s[k0][q] = ai0[q]; gh_s[k0][q] = ah0[q];
            gi_s[k1][q] = ai1[q]; gh_s[k1][q] = ah1[q];
        }
    }
    __syncthreads();

    for (int p = tid; p < GPB * H; p += 512) {
        int q = p / H, jj = p - q * H;
        float r = sigmoidf_(gi_s[jj][q] + gh_s[jj][q]);
        float u = sigmoidf_(gi_s[H + jj][q] + gh_s[H + jj][q]);
        float nn = tanhf(gi_s[2 * H + jj][q] + r * gh_s[2 * H + jj][q]);
        gf_out[(gbase + q) * H + jj] = (1.f - u) * nn + u * gfs[q][jj];
    }
}

extern "C" void kernel_launch(void* const* d_in, const int* in_sizes, int n_in,
                              void* d_out, int out_size, void* d_ws, size_t ws_size,
                              hipStream_t stream) {
    const float* node_feat = (const float*)d_in[0];
    const float* edge_feat = (const float*)d_in[1];
    const int* src = (const int*)d_in[2];
    const float* node_W = (const float*)d_in[5];
    const float* node_b = (const float*)d_in[6];
    const float* edge_W = (const float*)d_in[7];
    const float* edge_b = (const float*)d_in[8];
    const float* gnn_W = (const float*)d_in[9];
    const float* gnn_b = (const float*)d_in[10];
    const float* lg_W = (const float*)d_in[11];
    const float* lg_b = (const float*)d_in[12];
    const float* pr_W = (const float*)d_in[13];
    const float* pr_b = (const float*)d_in[14];
    const float* W_ih = (const float*)d_in[15];
    const float* W_hh = (const float*)d_in[16];
    const float* b_ih = (const float*)d_in[17];
    const float* b_hh = (const float*)d_in[18];
    float* out = (float*)d_out;

    char* ws = (char*)d_ws;
    size_t off = 0;
    auto alloc = [&](size_t bytes) { void* p = ws + off; off += (bytes + 4095) & ~(size_t)4095; return p; };
    float* h = (float*)alloc((size_t)V * H * 4);
    unsigned short* Aedge = (unsigned short*)alloc((size_t)NE * EK * 2);
    unsigned short* WtHi = (unsigned short*)alloc((size_t)NL * NP * KP * 2);
    unsigned short* WtLo = (unsigned short*)alloc((size_t)NL * NP * KP * 2);
    unsigned short* eWp = (unsigned short*)alloc((size_t)NP * 64 * 2);
    float* gf_ws = (float*)alloc((size_t)G * H * 4);
    float* wh_ws = (float*)alloc((size_t)G * H * 4);
    // WgT reuses the Aedge buffer (dead after k_mega): 1.92MB << 16.8MB.
    // Footprint identical to the R7-proven layout.
    float* WgT = (float*)Aedge;

    k_prep_embed<<<EFB + WBLOCKS + EMBB, 256, 0, stream>>>(
        edge_feat, gnn_W, edge_W, edge_b, node_feat, node_W, node_b,
        Aedge, WtHi, WtLo, eWp, h);

    k_mega<<<G, 256, 0, stream>>>(h, Aedge, eWp, src, WtHi, WtLo, gnn_b, gf_ws,
                                  lg_W, lg_b, wh_ws);

    k_wgt<<<TBLOCKS, 256, 0, stream>>>(W_ih, W_hh, WgT);

    // t = 0
    k_projgru<<<G / GPB, 512, 0, stream>>>(wh_ws, gf_ws, pr_W, pr_b,
                                           WgT, b_ih, b_hh, gf_ws);
    // t = 1
    k_attn<<<G, 256, 0, stream>>>(h, gf_ws, lg_W + 2 * H, lg_b + 1, wh_ws);
    k_projgru<<<G / GPB, 512, 0, stream>>>(wh_ws, gf_ws, pr_W + (size_t)H * H,
                                           pr_b + H,
                                           WgT + (size_t)2 * 3 * H * H,
                                           b_ih + 3 * H, b_hh + 3 * H, out);
}